// Round 1
// baseline (2779.333 us; speedup 1.0000x reference)
//
#include <hip/hip_runtime.h>
#include <cstdint>
#include <cstddef>

// Problem constants (shapes fixed by the reference)
#define F_IN   128
#define HC1    64    // heads1*ch1 = 8*8
#define CH2_   16
#define NB     64    // batch graphs

__device__ __forceinline__ void atomicMaxF(float* addr, float val) {
  val += 0.0f;  // canonicalize -0.0 -> +0.0 so the sign-split trick is safe
  if (val >= 0.0f) atomicMax((int*)addr, __float_as_int(val));
  else             atomicMin((unsigned int*)addr, __float_as_uint(val));
}

__global__ void fill_f32(float* __restrict__ p, float v, int n) {
  int i = blockIdx.x * blockDim.x + threadIdx.x;
  int stride = gridDim.x * blockDim.x;
  for (; i < n; i += stride) p[i] = v;
}

// y[n][M] = x[n][K] @ W[K][M] + b ; W staged in LDS; one wave handles 64/M nodes
template<int K, int M>
__global__ void gemm_small(const float* __restrict__ x, const float* __restrict__ W,
                           const float* __restrict__ b, float* __restrict__ y, int n) {
  __shared__ float Ws[K * M];
  __shared__ float bs[M];
  for (int i = threadIdx.x; i < K * M; i += blockDim.x) Ws[i] = W[i];
  for (int i = threadIdx.x; i < M; i += blockDim.x) bs[i] = b[i];
  __syncthreads();
  constexpr int NPW = 64 / M;  // nodes per wave
  int lane  = threadIdx.x & 63;
  int wave  = (blockIdx.x * blockDim.x + threadIdx.x) >> 6;
  int nwav  = (gridDim.x * blockDim.x) >> 6;
  int col   = lane % M;
  int noff  = lane / M;
  for (int base = wave * NPW; base < n; base += nwav * NPW) {
    int node = base + noff;
    if (node >= n) continue;
    const float* xp = x + (size_t)node * K;
    float acc = bs[col];
#pragma unroll
    for (int k = 0; k < K; k += 4) {
      float4 xv = *reinterpret_cast<const float4*>(xp + k);
      acc += xv.x * Ws[(k + 0) * M + col];
      acc += xv.y * Ws[(k + 1) * M + col];
      acc += xv.z * Ws[(k + 2) * M + col];
      acc += xv.w * Ws[(k + 3) * M + col];
    }
    y[(size_t)node * M + col] = acc;
  }
}

// ---------------- Layer 1: heads=8, ch=8 (64 lanes = 64 (h,c) pairs) ----------

__global__ void edge_logits_h8(const int* __restrict__ ei, int E, int E2,
                               const float* __restrict__ xl, const float* __restrict__ xr,
                               const float* __restrict__ att,
                               float* __restrict__ logits, float* __restrict__ mx) {
  int lane = threadIdx.x & 63;
  int e = blockIdx.x * 4 + (threadIdx.x >> 6);
  if (e >= E2) return;
  int s, d;
  if (e < E) { s = ei[e]; d = ei[E + e]; } else { s = d = e - E; }
  float a = xl[(size_t)s * 64 + lane] + xr[(size_t)d * 64 + lane];
  a = a > 0.0f ? a : 0.2f * a;            // leaky_relu(., 0.2)
  float v = a * att[lane];                // att[h][c], lane = h*8+c
  v += __shfl_xor(v, 1);
  v += __shfl_xor(v, 2);
  v += __shfl_xor(v, 4);                  // sum over c within each head group
  if ((lane & 7) == 0) {
    int h = lane >> 3;
    logits[(size_t)e * 8 + h] = v;
    atomicMaxF(&mx[(size_t)d * 8 + h], v);
  }
}

__global__ void edge_agg_h8(const int* __restrict__ ei, int E, int E2,
                            const float* __restrict__ xl,
                            const float* __restrict__ logits, const float* __restrict__ mx,
                            float* __restrict__ acc, float* __restrict__ denom) {
  int lane = threadIdx.x & 63;
  int e = blockIdx.x * 4 + (threadIdx.x >> 6);
  if (e >= E2) return;
  int s, d;
  if (e < E) { s = ei[e]; d = ei[E + e]; } else { s = d = e - E; }
  int h = lane >> 3;
  float ex = __expf(logits[(size_t)e * 8 + h] - mx[(size_t)d * 8 + h]);
  float xv = xl[(size_t)s * 64 + lane];
  atomicAdd(&acc[(size_t)d * 64 + lane], ex * xv);
  if ((lane & 7) == 0) atomicAdd(&denom[(size_t)d * 8 + h], ex);
}

__global__ void finish1(float* __restrict__ acc, const float* __restrict__ denom,
                        const float* __restrict__ bias, int n) {
  int i = blockIdx.x * blockDim.x + threadIdx.x;
  if (i >= n * 64) return;
  int node = i >> 6, col = i & 63, h = col >> 3;
  float v = acc[i] / (denom[(size_t)node * 8 + h] + 1e-16f) + bias[col];
  acc[i] = v > 0.0f ? v : (__expf(v) - 1.0f);   // elu after conv1
}

// ---------------- Layer 2: heads=1, ch=16 (16 lanes/edge, 4 edges/wave) -------

__global__ void edge_logits_h1(const int* __restrict__ ei, int E, int E2,
                               const float* __restrict__ xl, const float* __restrict__ xr,
                               const float* __restrict__ att,
                               float* __restrict__ logits, float* __restrict__ mx) {
  int lane = threadIdx.x & 63;
  int wave = blockIdx.x * 4 + (threadIdx.x >> 6);
  int e = wave * 4 + (lane >> 4);
  if (e >= E2) return;
  int c = lane & 15;
  int s, d;
  if (e < E) { s = ei[e]; d = ei[E + e]; } else { s = d = e - E; }
  float a = xl[(size_t)s * 16 + c] + xr[(size_t)d * 16 + c];
  a = a > 0.0f ? a : 0.2f * a;
  float v = a * att[c];
  v += __shfl_xor(v, 1);
  v += __shfl_xor(v, 2);
  v += __shfl_xor(v, 4);
  v += __shfl_xor(v, 8);
  if (c == 0) {
    logits[e] = v;
    atomicMaxF(&mx[d], v);
  }
}

__global__ void edge_agg_h1(const int* __restrict__ ei, int E, int E2,
                            const float* __restrict__ xl,
                            const float* __restrict__ logits, const float* __restrict__ mx,
                            float* __restrict__ acc, float* __restrict__ denom) {
  int lane = threadIdx.x & 63;
  int wave = blockIdx.x * 4 + (threadIdx.x >> 6);
  int e = wave * 4 + (lane >> 4);
  if (e >= E2) return;
  int c = lane & 15;
  int s, d;
  if (e < E) { s = ei[e]; d = ei[E + e]; } else { s = d = e - E; }
  float ex = __expf(logits[e] - mx[d]);
  float xv = xl[(size_t)s * 16 + c];
  atomicAdd(&acc[(size_t)d * 16 + c], ex * xv);
  if (c == 0) atomicAdd(&denom[d], ex);
}

__global__ void finish2(float* __restrict__ acc, const float* __restrict__ denom,
                        const float* __restrict__ bias, int n) {
  int i = blockIdx.x * blockDim.x + threadIdx.x;
  if (i >= n * 16) return;
  int node = i >> 4, col = i & 15;
  acc[i] = acc[i] / (denom[node] + 1e-16f) + bias[col];  // no elu after conv2
}

// ---------------- Pooling + classifier ---------------------------------------

__global__ void pool_kernel(const float* __restrict__ h2, const int* __restrict__ batch,
                            float* __restrict__ sums, float* __restrict__ cnts, int n) {
  __shared__ float ls[NB * CH2_];
  __shared__ float lc[NB];
  for (int i = threadIdx.x; i < NB * CH2_; i += blockDim.x) ls[i] = 0.0f;
  for (int i = threadIdx.x; i < NB; i += blockDim.x) lc[i] = 0.0f;
  __syncthreads();
  int total = n * 16;
  int stride = gridDim.x * blockDim.x;
  for (int i = blockIdx.x * blockDim.x + threadIdx.x; i < total; i += stride) {
    int node = i >> 4, c = i & 15;
    int b = batch[node];
    atomicAdd(&ls[b * 16 + c], h2[i]);
    if (c == 0) atomicAdd(&lc[b], 1.0f);
  }
  __syncthreads();
  for (int i = threadIdx.x; i < NB * CH2_; i += blockDim.x)
    if (ls[i] != 0.0f) atomicAdd(&sums[i], ls[i]);
  for (int i = threadIdx.x; i < NB; i += blockDim.x)
    if (lc[i] != 0.0f) atomicAdd(&cnts[i], lc[i]);
}

__global__ void classifier(const float* __restrict__ sums, const float* __restrict__ cnts,
                           const float* __restrict__ Wc, const float* __restrict__ bc,
                           float* __restrict__ out) {
  int b = threadIdx.x;
  if (b >= NB) return;
  float cnt = cnts[b];
  cnt = cnt > 1.0f ? cnt : 1.0f;
  float acc = 0.0f;
  for (int c = 0; c < 16; ++c) {
    float p = sums[b * 16 + c] / cnt;
    out[NB + b * 16 + c] = p;   // pooled, output 1
    acc += p * Wc[c];
  }
  out[b] = acc + bc[0];         // out, output 0
}

extern "C" void kernel_launch(void* const* d_in, const int* in_sizes, int n_in,
                              void* d_out, int out_size, void* d_ws, size_t ws_size,
                              hipStream_t stream) {
  const float* x     = (const float*)d_in[0];
  const int*   ei    = (const int*)d_in[1];
  const int*   batch = (const int*)d_in[2];
  const float* Wl1   = (const float*)d_in[3];
  const float* bl1   = (const float*)d_in[4];
  const float* Wr1   = (const float*)d_in[5];
  const float* br1   = (const float*)d_in[6];
  const float* att1  = (const float*)d_in[7];
  const float* bias1 = (const float*)d_in[8];
  const float* Wl2   = (const float*)d_in[9];
  const float* bl2   = (const float*)d_in[10];
  const float* Wr2   = (const float*)d_in[11];
  const float* br2   = (const float*)d_in[12];
  const float* att2  = (const float*)d_in[13];
  const float* bias2 = (const float*)d_in[14];
  const float* Wc    = (const float*)d_in[15];
  const float* bc    = (const float*)d_in[16];
  float* out = (float*)d_out;

  const int N  = in_sizes[0] / F_IN;
  const int E  = in_sizes[1] / 2;
  const int E2 = E + N;

  // Workspace layout (floats), with layer-2 reuse of layer-1 regions:
  float* ws = (float*)d_ws;
  float* xl1    = ws;                         // N*64
  float* xr1    = xl1 + (size_t)N * 64;       // N*64
  float* acc1   = xr1 + (size_t)N * 64;       // N*64  (becomes h1)
  float* logit1 = acc1 + (size_t)N * 64;      // E2*8
  float* mx1    = logit1 + (size_t)E2 * 8;    // N*8
  float* denom1 = mx1 + (size_t)N * 8;        // N*8
  float* sums   = denom1 + (size_t)N * 8;     // 64*16
  float* cnts   = sums + NB * CH2_;           // 64
  // layer-2 overlays (xl1/xr1/logit1/mx1 regions are dead by then)
  float* xl2    = xl1;                        // N*16
  float* xr2    = xl1 + (size_t)N * 16;       // N*16
  float* acc2   = xl1 + (size_t)N * 32;       // N*16  (becomes h2)
  float* logit2 = logit1;                     // E2
  float* mx2    = mx1;                        // N
  float* denom2 = mx1 + N;                    // N

  const float NEG_INF = -__builtin_huge_valf();

  // ---- layer 1 ----
  gemm_small<F_IN, HC1><<<2048, 256, 0, stream>>>(x, Wl1, bl1, xl1, N);
  gemm_small<F_IN, HC1><<<2048, 256, 0, stream>>>(x, Wr1, br1, xr1, N);
  fill_f32<<<1024, 256, 0, stream>>>(mx1, NEG_INF, N * 8);
  fill_f32<<<1024, 256, 0, stream>>>(denom1, 0.0f, N * 8);
  fill_f32<<<2048, 256, 0, stream>>>(acc1, 0.0f, N * 64);
  {
    int blocks = (E2 + 3) / 4;
    edge_logits_h8<<<blocks, 256, 0, stream>>>(ei, E, E2, xl1, xr1, att1, logit1, mx1);
    edge_agg_h8<<<blocks, 256, 0, stream>>>(ei, E, E2, xl1, logit1, mx1, acc1, denom1);
  }
  finish1<<<(N * 64 + 255) / 256, 256, 0, stream>>>(acc1, denom1, bias1, N);

  // ---- layer 2 ----
  gemm_small<HC1, CH2_><<<1024, 256, 0, stream>>>(acc1, Wl2, bl2, xl2, N);
  gemm_small<HC1, CH2_><<<1024, 256, 0, stream>>>(acc1, Wr2, br2, xr2, N);
  fill_f32<<<256, 256, 0, stream>>>(mx2, NEG_INF, N);
  fill_f32<<<256, 256, 0, stream>>>(denom2, 0.0f, N);
  fill_f32<<<1024, 256, 0, stream>>>(acc2, 0.0f, N * 16);
  {
    int blocks = (E2 + 15) / 16;
    edge_logits_h1<<<blocks, 256, 0, stream>>>(ei, E, E2, xl2, xr2, att2, logit2, mx2);
    edge_agg_h1<<<blocks, 256, 0, stream>>>(ei, E, E2, xl2, logit2, mx2, acc2, denom2);
  }
  finish2<<<(N * 16 + 255) / 256, 256, 0, stream>>>(acc2, denom2, bias2, N);

  // ---- pooling + classifier ----
  fill_f32<<<4, 256, 0, stream>>>(sums, 0.0f, NB * CH2_ + NB);  // sums then cnts (contiguous)
  pool_kernel<<<256, 256, 0, stream>>>(acc2, batch, sums, cnts, N);
  classifier<<<1, 64, 0, stream>>>(sums, cnts, Wc, bc, out);
}

// Round 2
// 1360.694 us; speedup vs baseline: 2.0426x; 2.0426x over previous
//
#include <hip/hip_runtime.h>
#include <cstdint>
#include <cstddef>

// Problem constants (shapes fixed by the reference)
#define F_IN   128
#define HC1    64    // heads1*ch1 = 8*8
#define CH2_   16
#define NB     64    // batch graphs

__device__ __forceinline__ void atomicMaxF(float* addr, float val) {
  val += 0.0f;  // canonicalize -0.0 -> +0.0 so the sign-split trick is safe
  if (val >= 0.0f) atomicMax((int*)addr, __float_as_int(val));
  else             atomicMin((unsigned int*)addr, __float_as_uint(val));
}

__global__ void fill_f32(float* __restrict__ p, float v, int n) {
  int i = blockIdx.x * blockDim.x + threadIdx.x;
  int stride = gridDim.x * blockDim.x;
  for (; i < n; i += stride) p[i] = v;
}

// y[n][M] = x[n][K] @ W[K][M] + b
// LDS-tiled: BM nodes per block, W staged once, x staged with coalesced float4
// loads (NO per-lane-broadcast global reads — that was the round-1 2GB/dispatch
// pathology). Compute: thread (ng,col) register-blocks NN nodes; Ws reads are
// lane-consecutive (conflict-free), xs reads are wave-broadcast float4 with
// +4-float row padding to de-bank the M=16 instance.
template<int K, int M, int BM>
__global__ void gemm_tile(const float* __restrict__ x, const float* __restrict__ W,
                          const float* __restrict__ b, float* __restrict__ y, int n) {
  constexpr int KP = K + 4;            // padded LDS row stride (floats), %4==0
  constexpr int GROUPS = 256 / M;      // node-groups per block
  constexpr int NN = BM / GROUPS;      // nodes per thread
  __shared__ float Ws[K * M];
  __shared__ float xs[BM * KP];
  const int t = threadIdx.x;
  const int node0 = blockIdx.x * BM;

  // stage W [K][M] (contiguous, coalesced float4)
  for (int i = t; i < K * M / 4; i += 256)
    reinterpret_cast<float4*>(Ws)[i] = reinterpret_cast<const float4*>(W)[i];
  // stage x tile: BM rows of K floats, coalesced float4, zero-fill tail
  for (int i = t; i < BM * (K / 4); i += 256) {
    int row = i / (K / 4);
    int kk  = (i % (K / 4)) * 4;
    int node = node0 + row;
    float4 v = make_float4(0.f, 0.f, 0.f, 0.f);
    if (node < n) v = *reinterpret_cast<const float4*>(x + (size_t)node * K + kk);
    *reinterpret_cast<float4*>(xs + row * KP + kk) = v;
  }
  __syncthreads();

  const int col = t % M;
  const int ng  = t / M;
  const float bias = b[col];
  float acc[NN];
#pragma unroll
  for (int nn = 0; nn < NN; ++nn) acc[nn] = bias;

  for (int k = 0; k < K; k += 4) {
    float w0 = Ws[(k + 0) * M + col];
    float w1 = Ws[(k + 1) * M + col];
    float w2 = Ws[(k + 2) * M + col];
    float w3 = Ws[(k + 3) * M + col];
#pragma unroll
    for (int nn = 0; nn < NN; ++nn) {
      float4 xv = *reinterpret_cast<const float4*>(xs + (ng * NN + nn) * KP + k);
      acc[nn] += xv.x * w0 + xv.y * w1 + xv.z * w2 + xv.w * w3;
    }
  }
#pragma unroll
  for (int nn = 0; nn < NN; ++nn) {
    int node = node0 + ng * NN + nn;
    if (node < n) y[(size_t)node * M + col] = acc[nn];
  }
}

// ---------------- Layer 1: heads=8, ch=8 (64 lanes = 64 (h,c) pairs) ----------

__global__ void edge_logits_h8(const int* __restrict__ ei, int E, int E2,
                               const float* __restrict__ xl, const float* __restrict__ xr,
                               const float* __restrict__ att,
                               float* __restrict__ logits, float* __restrict__ mx) {
  int lane = threadIdx.x & 63;
  int e = blockIdx.x * 4 + (threadIdx.x >> 6);
  if (e >= E2) return;
  int s, d;
  if (e < E) { s = ei[e]; d = ei[E + e]; } else { s = d = e - E; }
  float a = xl[(size_t)s * 64 + lane] + xr[(size_t)d * 64 + lane];
  a = a > 0.0f ? a : 0.2f * a;            // leaky_relu(., 0.2)
  float v = a * att[lane];                // att[h][c], lane = h*8+c
  v += __shfl_xor(v, 1);
  v += __shfl_xor(v, 2);
  v += __shfl_xor(v, 4);                  // sum over c within each head group
  if ((lane & 7) == 0) {
    int h = lane >> 3;
    logits[(size_t)e * 8 + h] = v;
    atomicMaxF(&mx[(size_t)d * 8 + h], v);
  }
}

__global__ void edge_agg_h8(const int* __restrict__ ei, int E, int E2,
                            const float* __restrict__ xl,
                            const float* __restrict__ logits, const float* __restrict__ mx,
                            float* __restrict__ acc, float* __restrict__ denom) {
  int lane = threadIdx.x & 63;
  int e = blockIdx.x * 4 + (threadIdx.x >> 6);
  if (e >= E2) return;
  int s, d;
  if (e < E) { s = ei[e]; d = ei[E + e]; } else { s = d = e - E; }
  int h = lane >> 3;
  float ex = __expf(logits[(size_t)e * 8 + h] - mx[(size_t)d * 8 + h]);
  float xv = xl[(size_t)s * 64 + lane];
  atomicAdd(&acc[(size_t)d * 64 + lane], ex * xv);
  if ((lane & 7) == 0) atomicAdd(&denom[(size_t)d * 8 + h], ex);
}

__global__ void finish1(float* __restrict__ acc, const float* __restrict__ denom,
                        const float* __restrict__ bias, int n) {
  int i = blockIdx.x * blockDim.x + threadIdx.x;
  if (i >= n * 64) return;
  int node = i >> 6, col = i & 63, h = col >> 3;
  float v = acc[i] / (denom[(size_t)node * 8 + h] + 1e-16f) + bias[col];
  acc[i] = v > 0.0f ? v : (__expf(v) - 1.0f);   // elu after conv1
}

// ---------------- Layer 2: heads=1, ch=16 (16 lanes/edge, 4 edges/wave) -------

__global__ void edge_logits_h1(const int* __restrict__ ei, int E, int E2,
                               const float* __restrict__ xl, const float* __restrict__ xr,
                               const float* __restrict__ att,
                               float* __restrict__ logits, float* __restrict__ mx) {
  int lane = threadIdx.x & 63;
  int wave = blockIdx.x * 4 + (threadIdx.x >> 6);
  int e = wave * 4 + (lane >> 4);
  if (e >= E2) return;
  int c = lane & 15;
  int s, d;
  if (e < E) { s = ei[e]; d = ei[E + e]; } else { s = d = e - E; }
  float a = xl[(size_t)s * 16 + c] + xr[(size_t)d * 16 + c];
  a = a > 0.0f ? a : 0.2f * a;
  float v = a * att[c];
  v += __shfl_xor(v, 1);
  v += __shfl_xor(v, 2);
  v += __shfl_xor(v, 4);
  v += __shfl_xor(v, 8);
  if (c == 0) {
    logits[e] = v;
    atomicMaxF(&mx[d], v);
  }
}

__global__ void edge_agg_h1(const int* __restrict__ ei, int E, int E2,
                            const float* __restrict__ xl,
                            const float* __restrict__ logits, const float* __restrict__ mx,
                            float* __restrict__ acc, float* __restrict__ denom) {
  int lane = threadIdx.x & 63;
  int wave = blockIdx.x * 4 + (threadIdx.x >> 6);
  int e = wave * 4 + (lane >> 4);
  if (e >= E2) return;
  int c = lane & 15;
  int s, d;
  if (e < E) { s = ei[e]; d = ei[E + e]; } else { s = d = e - E; }
  float ex = __expf(logits[e] - mx[d]);
  float xv = xl[(size_t)s * 16 + c];
  atomicAdd(&acc[(size_t)d * 16 + c], ex * xv);
  if (c == 0) atomicAdd(&denom[d], ex);
}

__global__ void finish2(float* __restrict__ acc, const float* __restrict__ denom,
                        const float* __restrict__ bias, int n) {
  int i = blockIdx.x * blockDim.x + threadIdx.x;
  if (i >= n * 16) return;
  int node = i >> 4, col = i & 15;
  acc[i] = acc[i] / (denom[node] + 1e-16f) + bias[col];  // no elu after conv2
}

// ---------------- Pooling + classifier ---------------------------------------

__global__ void pool_kernel(const float* __restrict__ h2, const int* __restrict__ batch,
                            float* __restrict__ sums, float* __restrict__ cnts, int n) {
  __shared__ float ls[NB * CH2_];
  __shared__ float lc[NB];
  for (int i = threadIdx.x; i < NB * CH2_; i += blockDim.x) ls[i] = 0.0f;
  for (int i = threadIdx.x; i < NB; i += blockDim.x) lc[i] = 0.0f;
  __syncthreads();
  int total = n * 16;
  int stride = gridDim.x * blockDim.x;
  for (int i = blockIdx.x * blockDim.x + threadIdx.x; i < total; i += stride) {
    int node = i >> 4, c = i & 15;
    int b = batch[node];
    atomicAdd(&ls[b * 16 + c], h2[i]);
    if (c == 0) atomicAdd(&lc[b], 1.0f);
  }
  __syncthreads();
  for (int i = threadIdx.x; i < NB * CH2_; i += blockDim.x)
    if (ls[i] != 0.0f) atomicAdd(&sums[i], ls[i]);
  for (int i = threadIdx.x; i < NB; i += blockDim.x)
    if (lc[i] != 0.0f) atomicAdd(&cnts[i], lc[i]);
}

__global__ void classifier(const float* __restrict__ sums, const float* __restrict__ cnts,
                           const float* __restrict__ Wc, const float* __restrict__ bc,
                           float* __restrict__ out) {
  int b = threadIdx.x;
  if (b >= NB) return;
  float cnt = cnts[b];
  cnt = cnt > 1.0f ? cnt : 1.0f;
  float acc = 0.0f;
  for (int c = 0; c < 16; ++c) {
    float p = sums[b * 16 + c] / cnt;
    out[NB + b * 16 + c] = p;   // pooled, output 1
    acc += p * Wc[c];
  }
  out[b] = acc + bc[0];         // out, output 0
}

extern "C" void kernel_launch(void* const* d_in, const int* in_sizes, int n_in,
                              void* d_out, int out_size, void* d_ws, size_t ws_size,
                              hipStream_t stream) {
  const float* x     = (const float*)d_in[0];
  const int*   ei    = (const int*)d_in[1];
  const int*   batch = (const int*)d_in[2];
  const float* Wl1   = (const float*)d_in[3];
  const float* bl1   = (const float*)d_in[4];
  const float* Wr1   = (const float*)d_in[5];
  const float* br1   = (const float*)d_in[6];
  const float* att1  = (const float*)d_in[7];
  const float* bias1 = (const float*)d_in[8];
  const float* Wl2   = (const float*)d_in[9];
  const float* bl2   = (const float*)d_in[10];
  const float* Wr2   = (const float*)d_in[11];
  const float* br2   = (const float*)d_in[12];
  const float* att2  = (const float*)d_in[13];
  const float* bias2 = (const float*)d_in[14];
  const float* Wc    = (const float*)d_in[15];
  const float* bc    = (const float*)d_in[16];
  float* out = (float*)d_out;

  const int N  = in_sizes[0] / F_IN;
  const int E  = in_sizes[1] / 2;
  const int E2 = E + N;

  // Workspace layout (floats), with layer-2 reuse of layer-1 regions:
  float* ws = (float*)d_ws;
  float* xl1    = ws;                         // N*64
  float* xr1    = xl1 + (size_t)N * 64;       // N*64
  float* acc1   = xr1 + (size_t)N * 64;       // N*64  (becomes h1)
  float* logit1 = acc1 + (size_t)N * 64;      // E2*8
  float* mx1    = logit1 + (size_t)E2 * 8;    // N*8
  float* denom1 = mx1 + (size_t)N * 8;        // N*8
  float* sums   = denom1 + (size_t)N * 8;     // 64*16
  float* cnts   = sums + NB * CH2_;           // 64
  // layer-2 overlays (xl1/xr1/logit1/mx1 regions are dead by then)
  float* xl2    = xl1;                        // N*16
  float* xr2    = xl1 + (size_t)N * 16;       // N*16
  float* acc2   = xl1 + (size_t)N * 32;       // N*16  (becomes h2)
  float* logit2 = logit1;                     // E2
  float* mx2    = mx1;                        // N
  float* denom2 = mx1 + N;                    // N

  const float NEG_INF = -__builtin_huge_valf();

  // ---- layer 1 ----
  gemm_tile<F_IN, HC1, 32><<<(N + 31) / 32, 256, 0, stream>>>(x, Wl1, bl1, xl1, N);
  gemm_tile<F_IN, HC1, 32><<<(N + 31) / 32, 256, 0, stream>>>(x, Wr1, br1, xr1, N);
  fill_f32<<<1024, 256, 0, stream>>>(mx1, NEG_INF, N * 8);
  fill_f32<<<1024, 256, 0, stream>>>(denom1, 0.0f, N * 8);
  fill_f32<<<2048, 256, 0, stream>>>(acc1, 0.0f, N * 64);
  {
    int blocks = (E2 + 3) / 4;
    edge_logits_h8<<<blocks, 256, 0, stream>>>(ei, E, E2, xl1, xr1, att1, logit1, mx1);
    edge_agg_h8<<<blocks, 256, 0, stream>>>(ei, E, E2, xl1, logit1, mx1, acc1, denom1);
  }
  finish1<<<(N * 64 + 255) / 256, 256, 0, stream>>>(acc1, denom1, bias1, N);

  // ---- layer 2 ----
  gemm_tile<HC1, CH2_, 64><<<(N + 63) / 64, 256, 0, stream>>>(acc1, Wl2, bl2, xl2, N);
  gemm_tile<HC1, CH2_, 64><<<(N + 63) / 64, 256, 0, stream>>>(acc1, Wr2, br2, xr2, N);
  fill_f32<<<256, 256, 0, stream>>>(mx2, NEG_INF, N);
  fill_f32<<<256, 256, 0, stream>>>(denom2, 0.0f, N);
  fill_f32<<<1024, 256, 0, stream>>>(acc2, 0.0f, N * 16);
  {
    int blocks = (E2 + 15) / 16;
    edge_logits_h1<<<blocks, 256, 0, stream>>>(ei, E, E2, xl2, xr2, att2, logit2, mx2);
    edge_agg_h1<<<blocks, 256, 0, stream>>>(ei, E, E2, xl2, logit2, mx2, acc2, denom2);
  }
  finish2<<<(N * 16 + 255) / 256, 256, 0, stream>>>(acc2, denom2, bias2, N);

  // ---- pooling + classifier ----
  fill_f32<<<4, 256, 0, stream>>>(sums, 0.0f, NB * CH2_ + NB);  // sums then cnts (contiguous)
  pool_kernel<<<256, 256, 0, stream>>>(acc2, batch, sums, cnts, N);
  classifier<<<1, 64, 0, stream>>>(sums, cnts, Wc, bc, out);
}

// Round 3
// 740.561 us; speedup vs baseline: 3.7530x; 1.8374x over previous
//
#include <hip/hip_runtime.h>
#include <cstdint>
#include <cstddef>

// Problem constants (shapes fixed by the reference)
#define F_IN   128
#define HC1    64    // heads1*ch1 = 8*8
#define CH2_   16
#define NB     64    // batch graphs

__global__ void fill_f32(float* __restrict__ p, float v, int n) {
  int i = blockIdx.x * blockDim.x + threadIdx.x;
  int stride = gridDim.x * blockDim.x;
  for (; i < n; i += stride) p[i] = v;
}

// ---------------- GEMM (round-2 tiled version, unchanged) ---------------------
template<int K, int M, int BM>
__global__ void gemm_tile(const float* __restrict__ x, const float* __restrict__ W,
                          const float* __restrict__ b, float* __restrict__ y, int n) {
  constexpr int KP = K + 4;
  constexpr int GROUPS = 256 / M;
  constexpr int NN = BM / GROUPS;
  __shared__ float Ws[K * M];
  __shared__ float xs[BM * KP];
  const int t = threadIdx.x;
  const int node0 = blockIdx.x * BM;
  for (int i = t; i < K * M / 4; i += 256)
    reinterpret_cast<float4*>(Ws)[i] = reinterpret_cast<const float4*>(W)[i];
  for (int i = t; i < BM * (K / 4); i += 256) {
    int row = i / (K / 4);
    int kk  = (i % (K / 4)) * 4;
    int node = node0 + row;
    float4 v = make_float4(0.f, 0.f, 0.f, 0.f);
    if (node < n) v = *reinterpret_cast<const float4*>(x + (size_t)node * K + kk);
    *reinterpret_cast<float4*>(xs + row * KP + kk) = v;
  }
  __syncthreads();
  const int col = t % M;
  const int ng  = t / M;
  const float bias = b[col];
  float acc[NN];
#pragma unroll
  for (int nn = 0; nn < NN; ++nn) acc[nn] = bias;
  for (int k = 0; k < K; k += 4) {
    float w0 = Ws[(k + 0) * M + col];
    float w1 = Ws[(k + 1) * M + col];
    float w2 = Ws[(k + 2) * M + col];
    float w3 = Ws[(k + 3) * M + col];
#pragma unroll
    for (int nn = 0; nn < NN; ++nn) {
      float4 xv = *reinterpret_cast<const float4*>(xs + (ng * NN + nn) * KP + k);
      acc[nn] += xv.x * w0 + xv.y * w1 + xv.z * w2 + xv.w * w3;
    }
  }
#pragma unroll
  for (int nn = 0; nn < NN; ++nn) {
    int node = node0 + ng * NN + nn;
    if (node < n) y[(size_t)node * M + col] = acc[nn];
  }
}

// ---------------- CSR build (by destination), rebuilt every call --------------

__global__ void hist_kernel(const int* __restrict__ ei, int E, int E2,
                            int* __restrict__ deg) {
  int e = blockIdx.x * blockDim.x + threadIdx.x;
  if (e >= E2) return;
  int d = (e < E) ? ei[E + e] : (e - E);
  atomicAdd(&deg[d], 1);
}

// per-256-chunk sums
__global__ void scan_partials(const int* __restrict__ deg, int* __restrict__ part, int n) {
  __shared__ int sh[256];
  int t = threadIdx.x;
  int i = blockIdx.x * 256 + t;
  sh[t] = (i < n) ? deg[i] : 0;
  __syncthreads();
  for (int off = 128; off > 0; off >>= 1) {
    if (t < off) sh[t] += sh[t + off];
    __syncthreads();
  }
  if (t == 0) part[blockIdx.x] = sh[0];
}

// single-wave exclusive scan of the partials (nblk <= a few thousand)
__global__ void scan_block(int* __restrict__ part, int nblk,
                           int* __restrict__ row_start, int n) {
  int lane = threadIdx.x;  // 64 threads
  int carry = 0;
  for (int base = 0; base < nblk; base += 64) {
    int i = base + lane;
    int orig = (i < nblk) ? part[i] : 0;
    int v = orig;
    for (int off = 1; off < 64; off <<= 1) {
      int u = __shfl_up(v, off);
      if (lane >= off) v += u;
    }
    if (i < nblk) part[i] = carry + (v - orig);   // exclusive block offset
    carry += __shfl(v, 63);
  }
  if (lane == 0) row_start[n] = carry;            // == E2
}

__global__ void scan_final(const int* __restrict__ deg, const int* __restrict__ part,
                           int* __restrict__ row_start, int n) {
  __shared__ int sh[256];
  int t = threadIdx.x;
  int i = blockIdx.x * 256 + t;
  int v = (i < n) ? deg[i] : 0;
  sh[t] = v;
  __syncthreads();
  for (int off = 1; off < 256; off <<= 1) {
    int u = (t >= off) ? sh[t - off] : 0;
    __syncthreads();
    sh[t] += u;
    __syncthreads();
  }
  if (i < n) row_start[i] = part[blockIdx.x] + sh[t] - v;
}

__global__ void scatter_kernel(const int* __restrict__ ei, int E, int E2,
                               const int* __restrict__ row_start,
                               int* __restrict__ cnt, int* __restrict__ csr_src) {
  int e = blockIdx.x * blockDim.x + threadIdx.x;
  if (e >= E2) return;
  int s, d;
  if (e < E) { s = ei[e]; d = ei[E + e]; } else { s = d = e - E; }
  int pos = row_start[d] + atomicAdd(&cnt[d], 1);
  csr_src[pos] = s;
}

// ---------------- Fused GATv2 layers: CSR + online softmax, zero float atomics

// Layer 1: heads=8 ch=8; one wave per node, lane = h*8+c
__global__ void fused_layer1(const int* __restrict__ row_start, const int* __restrict__ csr_src,
                             const float* __restrict__ xl, const float* __restrict__ xr,
                             const float* __restrict__ att, const float* __restrict__ bias,
                             float* __restrict__ out, int n) {
  int node = blockIdx.x * 4 + (threadIdx.x >> 6);
  if (node >= n) return;
  int lane = threadIdx.x & 63;
  float attv = att[lane];
  float xrv  = xr[(size_t)node * 64 + lane];
  int beg = row_start[node], end = row_start[node + 1];
  float m = -__builtin_huge_valf();
  float den = 0.0f, acc = 0.0f;
  for (int p = beg; p < end; ++p) {
    int s = csr_src[p];
    float xlv = xl[(size_t)s * 64 + lane];
    float a = xlv + xrv;
    a = a > 0.0f ? a : 0.2f * a;              // leaky_relu(., 0.2)
    float v = a * attv;
    v += __shfl_xor(v, 1);
    v += __shfl_xor(v, 2);
    v += __shfl_xor(v, 4);                    // per-head logit, broadcast in 8-lane group
    float nm = fmaxf(m, v);
    float scale = __expf(m - nm);             // m=-inf on first edge -> 0 (acc=den=0)
    float ex = __expf(v - nm);
    den = den * scale + ex;
    acc = acc * scale + ex * xlv;
    m = nm;
  }
  float o = acc / (den + 1e-16f) + bias[lane];
  out[(size_t)node * 64 + lane] = o > 0.0f ? o : (__expf(o) - 1.0f);  // elu
}

// Layer 2: heads=1 ch=16; 16 lanes per node, 16 nodes per 256-block
__global__ void fused_layer2(const int* __restrict__ row_start, const int* __restrict__ csr_src,
                             const float* __restrict__ xl, const float* __restrict__ xr,
                             const float* __restrict__ att, const float* __restrict__ bias,
                             float* __restrict__ out, int n) {
  int node = blockIdx.x * 16 + (threadIdx.x >> 4);
  if (node >= n) return;
  int c = threadIdx.x & 15;
  float attv = att[c];
  float xrv  = xr[(size_t)node * 16 + c];
  int beg = row_start[node], end = row_start[node + 1];
  float m = -__builtin_huge_valf();
  float den = 0.0f, acc = 0.0f;
  for (int p = beg; p < end; ++p) {
    int s = csr_src[p];
    float xlv = xl[(size_t)s * 16 + c];
    float a = xlv + xrv;
    a = a > 0.0f ? a : 0.2f * a;
    float v = a * attv;
    v += __shfl_xor(v, 1);
    v += __shfl_xor(v, 2);
    v += __shfl_xor(v, 4);
    v += __shfl_xor(v, 8);                    // logit, broadcast in 16-lane group
    float nm = fmaxf(m, v);
    float scale = __expf(m - nm);
    float ex = __expf(v - nm);
    den = den * scale + ex;
    acc = acc * scale + ex * xlv;
    m = nm;
  }
  out[(size_t)node * 16 + c] = acc / (den + 1e-16f) + bias[c];   // no elu after conv2
}

// ---------------- Pooling + classifier ---------------------------------------

__global__ void pool_kernel(const float* __restrict__ h2, const int* __restrict__ batch,
                            float* __restrict__ sums, float* __restrict__ cnts, int n) {
  __shared__ float ls[NB * CH2_];
  __shared__ float lc[NB];
  for (int i = threadIdx.x; i < NB * CH2_; i += blockDim.x) ls[i] = 0.0f;
  for (int i = threadIdx.x; i < NB; i += blockDim.x) lc[i] = 0.0f;
  __syncthreads();
  int total = n * 16;
  int stride = gridDim.x * blockDim.x;
  for (int i = blockIdx.x * blockDim.x + threadIdx.x; i < total; i += stride) {
    int node = i >> 4, c = i & 15;
    int b = batch[node];
    atomicAdd(&ls[b * 16 + c], h2[i]);
    if (c == 0) atomicAdd(&lc[b], 1.0f);
  }
  __syncthreads();
  for (int i = threadIdx.x; i < NB * CH2_; i += blockDim.x)
    if (ls[i] != 0.0f) atomicAdd(&sums[i], ls[i]);
  for (int i = threadIdx.x; i < NB; i += blockDim.x)
    if (lc[i] != 0.0f) atomicAdd(&cnts[i], lc[i]);
}

__global__ void classifier(const float* __restrict__ sums, const float* __restrict__ cnts,
                           const float* __restrict__ Wc, const float* __restrict__ bc,
                           float* __restrict__ out) {
  int b = threadIdx.x;
  if (b >= NB) return;
  float cnt = cnts[b];
  cnt = cnt > 1.0f ? cnt : 1.0f;
  float acc = 0.0f;
  for (int c = 0; c < 16; ++c) {
    float p = sums[b * 16 + c] / cnt;
    out[NB + b * 16 + c] = p;   // pooled, output 1
    acc += p * Wc[c];
  }
  out[b] = acc + bc[0];         // out, output 0
}

extern "C" void kernel_launch(void* const* d_in, const int* in_sizes, int n_in,
                              void* d_out, int out_size, void* d_ws, size_t ws_size,
                              hipStream_t stream) {
  const float* x     = (const float*)d_in[0];
  const int*   ei    = (const int*)d_in[1];
  const int*   batch = (const int*)d_in[2];
  const float* Wl1   = (const float*)d_in[3];
  const float* bl1   = (const float*)d_in[4];
  const float* Wr1   = (const float*)d_in[5];
  const float* br1   = (const float*)d_in[6];
  const float* att1  = (const float*)d_in[7];
  const float* bias1 = (const float*)d_in[8];
  const float* Wl2   = (const float*)d_in[9];
  const float* bl2   = (const float*)d_in[10];
  const float* Wr2   = (const float*)d_in[11];
  const float* br2   = (const float*)d_in[12];
  const float* att2  = (const float*)d_in[13];
  const float* bias2 = (const float*)d_in[14];
  const float* Wc    = (const float*)d_in[15];
  const float* bc    = (const float*)d_in[16];
  float* out = (float*)d_out;

  const int N  = in_sizes[0] / F_IN;
  const int E  = in_sizes[1] / 2;
  const int E2 = E + N;
  const int nblk = (N + 255) / 256;

  // Workspace layout
  float* base = (float*)d_ws;
  float* xl1  = base;                          // N*64
  float* xr1  = xl1 + (size_t)N * 64;          // N*64
  float* h1   = xr1 + (size_t)N * 64;          // N*64
  int* ideg   = (int*)(h1 + (size_t)N * 64);   // N
  int* icnt   = ideg + N;                      // N
  int* irow   = icnt + N;                      // N+1
  int* ipart  = irow + (N + 1);                // nblk
  int* icsr   = ipart + ((nblk + 63) & ~63);   // E2
  float* sums = (float*)(icsr + E2);           // NB*16
  float* cnts = sums + NB * CH2_;              // NB
  // layer-2 overlays on xl1 region (dead after fused_layer1 feeds h1)
  float* xl2  = xl1;                           // N*16
  float* xr2  = xl1 + (size_t)N * 16;          // N*16
  float* h2   = xl1 + (size_t)N * 32;          // N*16

  // ---- CSR build (shared by both layers) ----
  fill_f32<<<256, 256, 0, stream>>>((float*)ideg, 0.0f, 2 * N);   // deg + cnt = 0
  hist_kernel<<<(E2 + 255) / 256, 256, 0, stream>>>(ei, E, E2, ideg);
  scan_partials<<<nblk, 256, 0, stream>>>(ideg, ipart, N);
  scan_block<<<1, 64, 0, stream>>>(ipart, nblk, irow, N);
  scan_final<<<nblk, 256, 0, stream>>>(ideg, ipart, irow, N);
  scatter_kernel<<<(E2 + 255) / 256, 256, 0, stream>>>(ei, E, E2, irow, icnt, icsr);

  // ---- layer 1 ----
  gemm_tile<F_IN, HC1, 32><<<(N + 31) / 32, 256, 0, stream>>>(x, Wl1, bl1, xl1, N);
  gemm_tile<F_IN, HC1, 32><<<(N + 31) / 32, 256, 0, stream>>>(x, Wr1, br1, xr1, N);
  fused_layer1<<<(N + 3) / 4, 256, 0, stream>>>(irow, icsr, xl1, xr1, att1, bias1, h1, N);

  // ---- layer 2 ----
  gemm_tile<HC1, CH2_, 64><<<(N + 63) / 64, 256, 0, stream>>>(h1, Wl2, bl2, xl2, N);
  gemm_tile<HC1, CH2_, 64><<<(N + 63) / 64, 256, 0, stream>>>(h1, Wr2, br2, xr2, N);
  fused_layer2<<<(N + 15) / 16, 256, 0, stream>>>(irow, icsr, xl2, xr2, att2, bias2, h2, N);

  // ---- pooling + classifier ----
  fill_f32<<<4, 256, 0, stream>>>(sums, 0.0f, NB * CH2_ + NB);
  pool_kernel<<<256, 256, 0, stream>>>(h2, batch, sums, cnts, N);
  classifier<<<1, 64, 0, stream>>>(sums, cnts, Wc, bc, out);
}

// Round 4
// 490.792 us; speedup vs baseline: 5.6629x; 1.5089x over previous
//
#include <hip/hip_runtime.h>
#include <cstdint>
#include <cstddef>

// Problem constants (shapes fixed by the reference)
#define F_IN   128
#define HC1    64    // heads1*ch1 = 8*8
#define CH2_   16
#define NB     64    // batch graphs

__global__ void fill_f32(float* __restrict__ p, float v, int n) {
  int i = blockIdx.x * blockDim.x + threadIdx.x;
  int stride = gridDim.x * blockDim.x;
  for (; i < n; i += stride) p[i] = v;
}

// ---------------- DPP cross-lane reductions (full-rate VALU, no LDS pipe) -----
// ctrl: 0xB1 = quad_perm(1,0,3,2) = xor1 ; 0x4E = quad_perm(2,3,0,1) = xor2
// 0x141 = row_half_mirror (combines the two quads of each 8-group)
// 0x140 = row_mirror      (combines the two 8-halves of each 16-row)
template<int CTRL>
__device__ __forceinline__ float dpp_add(float v) {
  int j = __builtin_amdgcn_update_dpp(0, __float_as_int(v), CTRL, 0xF, 0xF, true);
  return v + __int_as_float(j);
}
__device__ __forceinline__ float sum8_dpp(float v) {   // sum over each 8-lane group
  v = dpp_add<0xB1>(v);
  v = dpp_add<0x4E>(v);
  v = dpp_add<0x141>(v);
  return v;
}
__device__ __forceinline__ float sum16_dpp(float v) {  // sum over each 16-lane row
  v = dpp_add<0xB1>(v);
  v = dpp_add<0x4E>(v);
  v = dpp_add<0x141>(v);
  v = dpp_add<0x140>(v);
  return v;
}

// ---------------- Dual-output GEMM: ya = x@Wa+ba, yb = x@Wb+bb ----------------
// x tile staged once in LDS (coalesced float4); W read from global
// (wave-coalesced rows, L1/L2-resident: 32-64 KB total).
template<int K, int M, int BM, bool PAD>
__global__ void gemm_dual(const float* __restrict__ x,
                          const float* __restrict__ Wa, const float* __restrict__ ba,
                          const float* __restrict__ Wb, const float* __restrict__ bb,
                          float* __restrict__ ya, float* __restrict__ yb, int n) {
  constexpr int KP = PAD ? K + 4 : K;   // pad only when a wave spans multiple rows
  constexpr int GROUPS = 256 / M;
  constexpr int NN = BM / GROUPS;
  __shared__ float xs[BM * KP];
  const int t = threadIdx.x;
  const int node0 = blockIdx.x * BM;
  for (int i = t; i < BM * (K / 4); i += 256) {
    int row = i / (K / 4);
    int kk  = (i % (K / 4)) * 4;
    int node = node0 + row;
    float4 v = make_float4(0.f, 0.f, 0.f, 0.f);
    if (node < n) v = *reinterpret_cast<const float4*>(x + (size_t)node * K + kk);
    *reinterpret_cast<float4*>(xs + row * KP + kk) = v;
  }
  __syncthreads();
  const int col = t % M;
  const int ng  = t / M;
  float accA[NN], accB[NN];
  const float biasA = ba[col], biasB = bb[col];
#pragma unroll
  for (int i = 0; i < NN; ++i) { accA[i] = biasA; accB[i] = biasB; }
  for (int k = 0; k < K; k += 4) {
    float wa0 = Wa[(k + 0) * M + col], wa1 = Wa[(k + 1) * M + col];
    float wa2 = Wa[(k + 2) * M + col], wa3 = Wa[(k + 3) * M + col];
    float wb0 = Wb[(k + 0) * M + col], wb1 = Wb[(k + 1) * M + col];
    float wb2 = Wb[(k + 2) * M + col], wb3 = Wb[(k + 3) * M + col];
#pragma unroll
    for (int nn = 0; nn < NN; ++nn) {
      float4 xv = *reinterpret_cast<const float4*>(xs + (ng * NN + nn) * KP + k);
      accA[nn] += xv.x * wa0 + xv.y * wa1 + xv.z * wa2 + xv.w * wa3;
      accB[nn] += xv.x * wb0 + xv.y * wb1 + xv.z * wb2 + xv.w * wb3;
    }
  }
#pragma unroll
  for (int nn = 0; nn < NN; ++nn) {
    int node = node0 + ng * NN + nn;
    if (node < n) {
      ya[(size_t)node * M + col] = accA[nn];
      yb[(size_t)node * M + col] = accB[nn];
    }
  }
}

// ---------------- CSR build (by destination), rebuilt every call --------------

__global__ void hist_kernel(const int* __restrict__ ei, int E, int E2,
                            int* __restrict__ deg) {
  int e = blockIdx.x * blockDim.x + threadIdx.x;
  if (e >= E2) return;
  int d = (e < E) ? ei[E + e] : (e - E);
  atomicAdd(&deg[d], 1);
}

__global__ void scan_partials(const int* __restrict__ deg, int* __restrict__ part, int n) {
  __shared__ int sh[256];
  int t = threadIdx.x;
  int i = blockIdx.x * 256 + t;
  sh[t] = (i < n) ? deg[i] : 0;
  __syncthreads();
  for (int off = 128; off > 0; off >>= 1) {
    if (t < off) sh[t] += sh[t + off];
    __syncthreads();
  }
  if (t == 0) part[blockIdx.x] = sh[0];
}

__global__ void scan_block(int* __restrict__ part, int nblk,
                           int* __restrict__ row_start, int n) {
  int lane = threadIdx.x;  // 64 threads
  int carry = 0;
  for (int base = 0; base < nblk; base += 64) {
    int i = base + lane;
    int orig = (i < nblk) ? part[i] : 0;
    int v = orig;
    for (int off = 1; off < 64; off <<= 1) {
      int u = __shfl_up(v, off);
      if (lane >= off) v += u;
    }
    if (i < nblk) part[i] = carry + (v - orig);
    carry += __shfl(v, 63);
  }
  if (lane == 0) row_start[n] = carry;  // == E2
}

__global__ void scan_final(const int* __restrict__ deg, const int* __restrict__ part,
                           int* __restrict__ row_start, int n) {
  __shared__ int sh[256];
  int t = threadIdx.x;
  int i = blockIdx.x * 256 + t;
  int v = (i < n) ? deg[i] : 0;
  sh[t] = v;
  __syncthreads();
  for (int off = 1; off < 256; off <<= 1) {
    int u = (t >= off) ? sh[t - off] : 0;
    __syncthreads();
    sh[t] += u;
    __syncthreads();
  }
  if (i < n) row_start[i] = part[blockIdx.x] + sh[t] - v;
}

__global__ void scatter_kernel(const int* __restrict__ ei, int E, int E2,
                               const int* __restrict__ row_start,
                               int* __restrict__ cnt, int* __restrict__ csr_src) {
  int e = blockIdx.x * blockDim.x + threadIdx.x;
  if (e >= E2) return;
  int s, d;
  if (e < E) { s = ei[e]; d = ei[E + e]; } else { s = d = e - E; }
  int pos = row_start[d] + atomicAdd(&cnt[d], 1);
  csr_src[pos] = s;
}

// ---------------- Fused GATv2 layers: CSR + online softmax --------------------
// 4x edge unroll: 4 gathers in flight, one max+rescale per chunk; DPP logits.

// Layer 1: heads=8 ch=8; one wave per node, lane = h*8+c
__global__ void fused_layer1(const int* __restrict__ row_start, const int* __restrict__ csr_src,
                             const float* __restrict__ xl, const float* __restrict__ xr,
                             const float* __restrict__ att, const float* __restrict__ bias,
                             float* __restrict__ out, int n) {
  int node = blockIdx.x * 4 + (threadIdx.x >> 6);
  if (node >= n) return;
  int lane = threadIdx.x & 63;
  const float attv = att[lane];
  const float xrv  = xr[(size_t)node * 64 + lane];
  const int beg = row_start[node], end = row_start[node + 1];
  float m = -__builtin_huge_valf();
  float den = 0.0f, acc = 0.0f;
  int p = beg;
  for (; p + 4 <= end; p += 4) {
    int s0 = csr_src[p + 0], s1 = csr_src[p + 1];
    int s2 = csr_src[p + 2], s3 = csr_src[p + 3];
    float x0 = xl[(size_t)s0 * 64 + lane];
    float x1 = xl[(size_t)s1 * 64 + lane];
    float x2 = xl[(size_t)s2 * 64 + lane];
    float x3 = xl[(size_t)s3 * 64 + lane];
    float a0 = x0 + xrv; a0 = a0 > 0.f ? a0 : 0.2f * a0;
    float a1 = x1 + xrv; a1 = a1 > 0.f ? a1 : 0.2f * a1;
    float a2 = x2 + xrv; a2 = a2 > 0.f ? a2 : 0.2f * a2;
    float a3 = x3 + xrv; a3 = a3 > 0.f ? a3 : 0.2f * a3;
    float v0 = sum8_dpp(a0 * attv);
    float v1 = sum8_dpp(a1 * attv);
    float v2 = sum8_dpp(a2 * attv);
    float v3 = sum8_dpp(a3 * attv);
    float nm = fmaxf(m, fmaxf(fmaxf(v0, v1), fmaxf(v2, v3)));
    float scale = __expf(m - nm);          // first chunk: exp(-inf)=0
    float e0 = __expf(v0 - nm), e1 = __expf(v1 - nm);
    float e2 = __expf(v2 - nm), e3 = __expf(v3 - nm);
    den = den * scale + ((e0 + e1) + (e2 + e3));
    acc = acc * scale + ((e0 * x0 + e1 * x1) + (e2 * x2 + e3 * x3));
    m = nm;
  }
  for (; p < end; ++p) {
    int s = csr_src[p];
    float xv = xl[(size_t)s * 64 + lane];
    float a = xv + xrv; a = a > 0.f ? a : 0.2f * a;
    float v = sum8_dpp(a * attv);
    float nm = fmaxf(m, v);
    float scale = __expf(m - nm);
    float ex = __expf(v - nm);
    den = den * scale + ex;
    acc = acc * scale + ex * xv;
    m = nm;
  }
  float o = acc / (den + 1e-16f) + bias[lane];
  out[(size_t)node * 64 + lane] = o > 0.0f ? o : (__expf(o) - 1.0f);  // elu
}

// Layer 2: heads=1 ch=16; 16 lanes per node, 16 nodes per 256-block
__global__ void fused_layer2(const int* __restrict__ row_start, const int* __restrict__ csr_src,
                             const float* __restrict__ xl, const float* __restrict__ xr,
                             const float* __restrict__ att, const float* __restrict__ bias,
                             float* __restrict__ out, int n) {
  int node = blockIdx.x * 16 + (threadIdx.x >> 4);
  if (node >= n) return;
  int c = threadIdx.x & 15;
  const float attv = att[c];
  const float xrv  = xr[(size_t)node * 16 + c];
  const int beg = row_start[node], end = row_start[node + 1];
  float m = -__builtin_huge_valf();
  float den = 0.0f, acc = 0.0f;
  int p = beg;
  for (; p + 4 <= end; p += 4) {
    int s0 = csr_src[p + 0], s1 = csr_src[p + 1];
    int s2 = csr_src[p + 2], s3 = csr_src[p + 3];
    float x0 = xl[(size_t)s0 * 16 + c];
    float x1 = xl[(size_t)s1 * 16 + c];
    float x2 = xl[(size_t)s2 * 16 + c];
    float x3 = xl[(size_t)s3 * 16 + c];
    float a0 = x0 + xrv; a0 = a0 > 0.f ? a0 : 0.2f * a0;
    float a1 = x1 + xrv; a1 = a1 > 0.f ? a1 : 0.2f * a1;
    float a2 = x2 + xrv; a2 = a2 > 0.f ? a2 : 0.2f * a2;
    float a3 = x3 + xrv; a3 = a3 > 0.f ? a3 : 0.2f * a3;
    float v0 = sum16_dpp(a0 * attv);
    float v1 = sum16_dpp(a1 * attv);
    float v2 = sum16_dpp(a2 * attv);
    float v3 = sum16_dpp(a3 * attv);
    float nm = fmaxf(m, fmaxf(fmaxf(v0, v1), fmaxf(v2, v3)));
    float scale = __expf(m - nm);
    float e0 = __expf(v0 - nm), e1 = __expf(v1 - nm);
    float e2 = __expf(v2 - nm), e3 = __expf(v3 - nm);
    den = den * scale + ((e0 + e1) + (e2 + e3));
    acc = acc * scale + ((e0 * x0 + e1 * x1) + (e2 * x2 + e3 * x3));
    m = nm;
  }
  for (; p < end; ++p) {
    int s = csr_src[p];
    float xv = xl[(size_t)s * 16 + c];
    float a = xv + xrv; a = a > 0.f ? a : 0.2f * a;
    float v = sum16_dpp(a * attv);
    float nm = fmaxf(m, v);
    float scale = __expf(m - nm);
    float ex = __expf(v - nm);
    den = den * scale + ex;
    acc = acc * scale + ex * xv;
    m = nm;
  }
  out[(size_t)node * 16 + c] = acc / (den + 1e-16f) + bias[c];   // no elu after conv2
}

// ---------------- Pooling + classifier ---------------------------------------

__global__ void pool_kernel(const float* __restrict__ h2, const int* __restrict__ batch,
                            float* __restrict__ sums, float* __restrict__ cnts, int n) {
  __shared__ float ls[NB * CH2_];
  __shared__ float lc[NB];
  for (int i = threadIdx.x; i < NB * CH2_; i += blockDim.x) ls[i] = 0.0f;
  for (int i = threadIdx.x; i < NB; i += blockDim.x) lc[i] = 0.0f;
  __syncthreads();
  int total = n * 16;
  int stride = gridDim.x * blockDim.x;
  for (int i = blockIdx.x * blockDim.x + threadIdx.x; i < total; i += stride) {
    int node = i >> 4, c = i & 15;
    int b = batch[node];
    atomicAdd(&ls[b * 16 + c], h2[i]);
    if (c == 0) atomicAdd(&lc[b], 1.0f);
  }
  __syncthreads();
  for (int i = threadIdx.x; i < NB * CH2_; i += blockDim.x)
    if (ls[i] != 0.0f) atomicAdd(&sums[i], ls[i]);
  for (int i = threadIdx.x; i < NB; i += blockDim.x)
    if (lc[i] != 0.0f) atomicAdd(&cnts[i], lc[i]);
}

__global__ void classifier(const float* __restrict__ sums, const float* __restrict__ cnts,
                           const float* __restrict__ Wc, const float* __restrict__ bc,
                           float* __restrict__ out) {
  int b = threadIdx.x;
  if (b >= NB) return;
  float cnt = cnts[b];
  cnt = cnt > 1.0f ? cnt : 1.0f;
  float acc = 0.0f;
  for (int c = 0; c < 16; ++c) {
    float p = sums[b * 16 + c] / cnt;
    out[NB + b * 16 + c] = p;   // pooled, output 1
    acc += p * Wc[c];
  }
  out[b] = acc + bc[0];         // out, output 0
}

extern "C" void kernel_launch(void* const* d_in, const int* in_sizes, int n_in,
                              void* d_out, int out_size, void* d_ws, size_t ws_size,
                              hipStream_t stream) {
  const float* x     = (const float*)d_in[0];
  const int*   ei    = (const int*)d_in[1];
  const int*   batch = (const int*)d_in[2];
  const float* Wl1   = (const float*)d_in[3];
  const float* bl1   = (const float*)d_in[4];
  const float* Wr1   = (const float*)d_in[5];
  const float* br1   = (const float*)d_in[6];
  const float* att1  = (const float*)d_in[7];
  const float* bias1 = (const float*)d_in[8];
  const float* Wl2   = (const float*)d_in[9];
  const float* bl2   = (const float*)d_in[10];
  const float* Wr2   = (const float*)d_in[11];
  const float* br2   = (const float*)d_in[12];
  const float* att2  = (const float*)d_in[13];
  const float* bias2 = (const float*)d_in[14];
  const float* Wc    = (const float*)d_in[15];
  const float* bc    = (const float*)d_in[16];
  float* out = (float*)d_out;

  const int N  = in_sizes[0] / F_IN;
  const int E  = in_sizes[1] / 2;
  const int E2 = E + N;
  const int nblk = (N + 255) / 256;

  // Workspace layout
  float* base = (float*)d_ws;
  float* xl1  = base;                          // N*64
  float* xr1  = xl1 + (size_t)N * 64;          // N*64
  float* h1   = xr1 + (size_t)N * 64;          // N*64
  int* ideg   = (int*)(h1 + (size_t)N * 64);   // N
  int* icnt   = ideg + N;                      // N
  int* irow   = icnt + N;                      // N+1
  int* ipart  = irow + (N + 1);                // nblk
  int* icsr   = ipart + ((nblk + 63) & ~63);   // E2
  float* sums = (float*)(icsr + E2);           // NB*16
  float* cnts = sums + NB * CH2_;              // NB
  // layer-2 overlays on xl1 region (dead after fused_layer1 feeds h1)
  float* xl2  = xl1;                           // N*16
  float* xr2  = xl1 + (size_t)N * 16;          // N*16
  float* h2   = xl1 + (size_t)N * 32;          // N*16

  // ---- CSR build (shared by both layers) ----
  fill_f32<<<256, 256, 0, stream>>>((float*)ideg, 0.0f, 2 * N);   // deg + cnt = 0
  hist_kernel<<<(E2 + 255) / 256, 256, 0, stream>>>(ei, E, E2, ideg);
  scan_partials<<<nblk, 256, 0, stream>>>(ideg, ipart, N);
  scan_block<<<1, 64, 0, stream>>>(ipart, nblk, irow, N);
  scan_final<<<nblk, 256, 0, stream>>>(ideg, ipart, irow, N);
  scatter_kernel<<<(E2 + 255) / 256, 256, 0, stream>>>(ei, E, E2, irow, icnt, icsr);

  // ---- layer 1 ----
  gemm_dual<F_IN, HC1, 64, false><<<(N + 63) / 64, 256, 0, stream>>>(
      x, Wl1, bl1, Wr1, br1, xl1, xr1, N);
  fused_layer1<<<(N + 3) / 4, 256, 0, stream>>>(irow, icsr, xl1, xr1, att1, bias1, h1, N);

  // ---- layer 2 ----
  gemm_dual<HC1, CH2_, 64, true><<<(N + 63) / 64, 256, 0, stream>>>(
      h1, Wl2, bl2, Wr2, br2, xl2, xr2, N);
  fused_layer2<<<(N + 15) / 16, 256, 0, stream>>>(irow, icsr, xl2, xr2, att2, bias2, h2, N);

  // ---- pooling + classifier ----
  fill_f32<<<4, 256, 0, stream>>>(sums, 0.0f, NB * CH2_ + NB);
  pool_kernel<<<256, 256, 0, stream>>>(h2, batch, sums, cnts, N);
  classifier<<<1, 64, 0, stream>>>(sums, cnts, Wc, bc, out);
}